// Round 8
// baseline (1284.624 us; speedup 1.0000x reference)
//
#include <hip/hip_runtime.h>
#include <hip/hip_bf16.h>

#define B_ 8
#define N_ 4096
#define K_ 16
#define D_ 128

typedef short bf16x8 __attribute__((ext_vector_type(8)));
typedef float f32x4 __attribute__((ext_vector_type(4)));

__device__ __forceinline__ short bfr(float x){
  __hip_bfloat16 h = __float2bfloat16(x);
  return *reinterpret_cast<short*>(&h);
}

// ---------------- prep: bf16 transposed weights + zero stats ----------------
__global__ __launch_bounds__(256) void prep_kernel(
    const float* __restrict__ W1, const float* __restrict__ Wf, const float* __restrict__ cw2,
    short* __restrict__ W1T, short* __restrict__ WfT, short* __restrict__ cw2b,
    float* __restrict__ stats)
{
  int t = blockIdx.x*256 + threadIdx.x;
  if (t < 16384) {                       // W1T[d][c] = W1[c][d]
    int d = t >> 7, c = t & 127;
    W1T[t] = bfr(W1[c*128 + d]);
  } else if (t < 49152) {                // WfT[d][c] = Wf[c][d]
    int u = t - 16384;
    int d = u >> 8, c = u & 255;
    WfT[u] = bfr(Wf[c*128 + d]);
  } else if (t < 57344) {                // cw2 already [d][c] row-major
    int u = t - 49152;
    cw2b[u] = bfr(cw2[u]);
  } else if (t < 57360) {
    stats[t - 57344] = 0.0f;
  }
}

// ---------------- knn ----------------
// plain insert (strict <): used in the ascending within-slice scan, where
// earlier-inserted == lower index, matching top_k tie semantics.
__device__ __forceinline__ void insert16(float (&bd)[16], int (&bi)[16], float d, int cid){
  #pragma unroll
  for (int j = 15; j >= 1; --j){
    bool ltj = d < bd[j];
    bool ltp = d < bd[j-1];
    float nd = ltj ? (ltp ? bd[j-1] : d) : bd[j];
    int   ni = ltj ? (ltp ? bi[j-1] : cid) : bi[j];
    bd[j] = nd; bi[j] = ni;
  }
  bool lt0 = d < bd[0];
  bd[0] = lt0 ? d : bd[0];
  bi[0] = lt0 ? cid : bi[0];
}

// (d, idx)-lexicographic insert: used in cross-slice merges so exact-f32 ties
// resolve to the LOWER INDEX regardless of merge-tree order (= top_k).
__device__ __forceinline__ void insert16t(float (&bd)[16], int (&bi)[16], float d, int cid){
  bool lt[16];
  #pragma unroll
  for (int j = 0; j < 16; ++j)
    lt[j] = (d < bd[j]) || ((d == bd[j]) && (cid < bi[j]));
  #pragma unroll
  for (int j = 15; j >= 1; --j){
    float nd = lt[j] ? (lt[j-1] ? bd[j-1] : d) : bd[j];
    int   ni = lt[j] ? (lt[j-1] ? bi[j-1] : cid) : bi[j];
    bd[j] = nd; bi[j] = ni;
  }
  if (lt[0]){ bd[0] = d; bi[0] = cid; }
}

// 512 threads = 8 waves; 64 queries/block; 8 CONTIGUOUS 512-cand slices per
// query, scanned in ascending true-index order. LDS XOR-swizzle (store+load)
// gives conflict-free reads. NOTE: no min-waves arg in launch_bounds — R7's
// (512,3) capped VGPRs at 52 and spilled bd[]/bi[] to scratch (834us).
__global__ __launch_bounds__(512) void knn_kernel(
    const float* __restrict__ xyz, int* __restrict__ idx_out, float* __restrict__ stats)
{
  __shared__ float4 cand[N_];            // 64 KB: x,y,z,|p|^2 (XOR-swizzled)
  int b    = blockIdx.x >> 6;            // 64 blocks per batch
  int qblk = (blockIdx.x & 63) << 6;     // 64 queries per block
  const float* xb = xyz + b*N_*3;
  for (int i = threadIdx.x; i < N_; i += 512){
    float x = xb[i*3+0], y = xb[i*3+1], z = xb[i*3+2];
    int e = i ^ ((i >> 9) & 7);          // swizzled slot (bijection within slice)
    cand[e] = make_float4(x, y, z, x*x + y*y + z*z);
  }
  __syncthreads();

  int wv = threadIdx.x >> 6, lane = threadIdx.x & 63;
  int q = lane & 7;                      // query within wave's 8
  int s = lane >> 3;                     // slice 0..7
  int qi = qblk + (wv << 3) + q;         // batch-local query index
  float4 qc = cand[qi ^ ((qi >> 9) & 7)];

  float bd[16]; int bi[16];
  #pragma unroll
  for (int j = 0; j < 16; ++j){ bd[j] = 3.4e38f; bi[j] = 0x7fffffff; }

  // ascending-index scan of contiguous slice [s*512, (s+1)*512)
  int cbase = s << 9;
  for (int m = 0; m < 512; ++m){
    int ci = cbase + m;                  // true candidate index (ascending)
    float4 c = cand[cbase + (m ^ s)];    // swizzled LDS slot -> conflict-free
    float t = qc.x*c.x + qc.y*c.y + qc.z*c.z;
    float d = (qc.w + c.w) - 2.0f*t;
    if (d < bd[15]) insert16(bd, bi, d, ci);
  }

  // absorb-tree merge over slice bits; tie-aware insert makes the result
  // independent of tree order.
  #pragma unroll
  for (int xm = 32; xm >= 8; xm >>= 1){
    bool absorb = (lane & xm) == 0;
    #pragma unroll
    for (int j = 0; j < 16; ++j){
      float pdj = __shfl_xor(bd[j], xm);
      int   pij = __shfl_xor(bi[j], xm);
      if (absorb) insert16t(bd, bi, pdj, pij);
    }
  }

  // lanes with s==0 own the final merged lists
  float sv[9];
  #pragma unroll
  for (int i = 0; i < 9; ++i) sv[i] = 0.0f;
  if (s == 0){
    int gq = b*N_ + qi;
    #pragma unroll
    for (int j = 0; j < 16; ++j){
      idx_out[gq*16 + j] = bi[j];
      int be = bi[j] ^ ((bi[j] >> 9) & 7);
      float4 c = cand[be];
      float rx = c.x - qc.x, ry = c.y - qc.y, rz = c.z - qc.z;
      sv[0] += rx;    sv[1] += ry;    sv[2] += rz;
      sv[3] += rx*rx; sv[4] += ry*ry; sv[5] += rz*rz;
      sv[6] += rx*ry; sv[7] += rx*rz; sv[8] += ry*rz;
    }
  }
  #pragma unroll
  for (int i = 0; i < 9; ++i){
    float v = sv[i];
    #pragma unroll
    for (int mask = 1; mask < 64; mask <<= 1) v += __shfl_xor(v, mask);
    if (lane == 0) atomicAdd(&stats[i], v);
  }
}

// ---------------- BN finalize ----------------
__global__ void bn_finalize_kernel(
    const float* __restrict__ stats, const float* __restrict__ cw1, const float* __restrict__ cb1,
    const float* __restrict__ bn_g, const float* __restrict__ bn_b,
    float* __restrict__ bnsc, float* __restrict__ bnsh)
{
  int o = threadIdx.x;
  if (o >= 64) return;
  const float inv = 1.0f / (float)(B_*N_*K_);
  float m1x = stats[0]*inv, m1y = stats[1]*inv, m1z = stats[2]*inv;
  float mxx = stats[3]*inv, myy = stats[4]*inv, mzz = stats[5]*inv;
  float mxy = stats[6]*inv, mxz = stats[7]*inv, myz = stats[8]*inv;
  float w0 = cw1[o*3], w1 = cw1[o*3+1], w2 = cw1[o*3+2], cb = cb1[o];
  float wm = w0*m1x + w1*m1y + w2*m1z;
  float mu = wm + cb;
  float e2 = w0*w0*mxx + w1*w1*myy + w2*w2*mzz
           + 2.0f*(w0*w1*mxy + w0*w2*mxz + w1*w2*myz)
           + 2.0f*cb*wm + cb*cb;
  float var = e2 - mu*mu;
  float sc = bn_g[o] * rsqrtf(var + 1e-5f);
  bnsc[o] = sc;
  bnsh[o] = bn_b[o] - mu*sc;
}

// ---------------- main fused kernel: 1 wave = 1 point ----------------
__global__ __launch_bounds__(256) void lga_main_kernel(
    const float* __restrict__ xyz, const float* __restrict__ feats, const int* __restrict__ idx_ws,
    const short* __restrict__ W1T, const short* __restrict__ WfT, const short* __restrict__ cw2b,
    const float* __restrict__ b1, const float* __restrict__ ln1g, const float* __restrict__ ln1b,
    const float* __restrict__ cw1, const float* __restrict__ cb1,
    const float* __restrict__ bnsc, const float* __restrict__ bnsh,
    const float* __restrict__ cb2, const float* __restrict__ bfb,
    const float* __restrict__ lnfg, const float* __restrict__ lnfb,
    const float* __restrict__ alpha, const float* __restrict__ beta,
    float* __restrict__ out)
{
  __shared__ short fuse[4][16][264];     // per-wave [16 rows][256+8 cols] bf16 concat buffer
  __shared__ float s_cw1[192], s_cb1[64], s_sc[64], s_sh[64];

  int tid = threadIdx.x;
  for (int i = tid; i < 192; i += 256) s_cw1[i] = cw1[i];
  if (tid < 64){ s_cb1[tid] = cb1[tid]; s_sc[tid] = bnsc[tid]; s_sh[tid] = bnsh[tid]; }
  __syncthreads();

  int wv = tid >> 6, lane = tid & 63, g = lane >> 4, c16 = lane & 15;
  int point = blockIdx.x*4 + wv;
  int bb = point >> 12, n = point & 4095;

  // per-lane column params (col = t*16 + c16)
  float p_b1[8], p_g1[8], p_e1[8], p_c2[8], p_bf[8], p_gf[8], p_ef[8], p_al[8], p_bt[8];
  #pragma unroll
  for (int t = 0; t < 8; ++t){
    int col = t*16 + c16;
    p_b1[t] = b1[col];  p_g1[t] = ln1g[col]; p_e1[t] = ln1b[col]; p_c2[t] = cb2[col];
    p_bf[t] = bfb[col]; p_gf[t] = lnfg[col]; p_ef[t] = lnfb[col];
    p_al[t] = alpha[col]; p_bt[t] = beta[col];
  }

  // A1 fragments: gathered neighbor features (row = c16, k-chunk = g*8 within each 32)
  int nb = idx_ws[point*16 + c16];
  const float* frow = feats + (bb*N_ + nb)*128;
  bf16x8 a1[4];
  #pragma unroll
  for (int ks = 0; ks < 4; ++ks){
    f32x4 lo = *(const f32x4*)(frow + ks*32 + g*8);
    f32x4 hi = *(const f32x4*)(frow + ks*32 + g*8 + 4);
    bf16x8 v;
    v[0]=bfr(lo[0]); v[1]=bfr(lo[1]); v[2]=bfr(lo[2]); v[3]=bfr(lo[3]);
    v[4]=bfr(hi[0]); v[5]=bfr(hi[1]); v[6]=bfr(hi[2]); v[7]=bfr(hi[3]);
    a1[ks] = v;
  }

  // GEMM1: nb_feat @ W1
  f32x4 acc[8];
  #pragma unroll
  for (int t = 0; t < 8; ++t) acc[t] = (f32x4){0.f,0.f,0.f,0.f};
  #pragma unroll
  for (int t = 0; t < 8; ++t){
    #pragma unroll
    for (int ks = 0; ks < 4; ++ks){
      bf16x8 w = *(const bf16x8*)(W1T + (t*16 + c16)*128 + ks*32 + g*8);
      acc[t] = __builtin_amdgcn_mfma_f32_16x16x32_bf16(a1[ks], w, acc[t], 0, 0, 0);
    }
  }

  // +b1, LayerNorm over 128 cols per row, SiLU -> fuse[:, 0:128]
  float sm[4] = {0,0,0,0}, sq[4] = {0,0,0,0};
  #pragma unroll
  for (int t = 0; t < 8; ++t){
    #pragma unroll
    for (int r = 0; r < 4; ++r){
      float v = acc[t][r] + p_b1[t];
      acc[t][r] = v;
      sm[r] += v; sq[r] += v*v;
    }
  }
  #pragma unroll
  for (int mask = 1; mask < 16; mask <<= 1){
    #pragma unroll
    for (int r = 0; r < 4; ++r){ sm[r] += __shfl_xor(sm[r], mask); sq[r] += __shfl_xor(sq[r], mask); }
  }
  float mean[4], rstd[4];
  #pragma unroll
  for (int r = 0; r < 4; ++r){
    mean[r] = sm[r] * (1.0f/128.0f);
    float var = sq[r]*(1.0f/128.0f) - mean[r]*mean[r];
    rstd[r] = rsqrtf(var + 1e-5f);
  }
  short* fw = &fuse[wv][0][0];
  #pragma unroll
  for (int t = 0; t < 8; ++t){
    #pragma unroll
    for (int r = 0; r < 4; ++r){
      float y = (acc[t][r] - mean[r]) * rstd[r] * p_g1[t] + p_e1[t];
      y = y / (1.0f + __expf(-y));       // SiLU
      fw[(g*4 + r)*264 + t*16 + c16] = bfr(y);
    }
  }

  // geo path: rel -> h (VALU, 16 outputs per lane in A2-fragment layout) -> GEMM2b
  float rx, ry, rz;
  {
    const float* cx = xyz + (bb*N_ + n)*3;
    const float* nx = xyz + (bb*N_ + nb)*3;
    rx = nx[0]-cx[0]; ry = nx[1]-cx[1]; rz = nx[2]-cx[2];
  }
  bf16x8 a2[2];
  #pragma unroll
  for (int ks = 0; ks < 2; ++ks){
    bf16x8 v;
    #pragma unroll
    for (int j = 0; j < 8; ++j){
      int o = ks*32 + g*8 + j;
      float h = s_cw1[o*3]*rx + s_cw1[o*3+1]*ry + s_cw1[o*3+2]*rz + s_cb1[o];
      h = h * s_sc[o] + s_sh[o];         // BatchNorm (precomputed global-stat affine)
      h = h / (1.0f + __expf(-h));       // SiLU
      v[j] = bfr(h);
    }
    a2[ks] = v;
  }
  #pragma unroll
  for (int t = 0; t < 8; ++t){
    f32x4 a = (f32x4){0.f,0.f,0.f,0.f};
    #pragma unroll
    for (int ks = 0; ks < 2; ++ks){
      bf16x8 w = *(const bf16x8*)(cw2b + (t*16 + c16)*64 + ks*32 + g*8);
      a = __builtin_amdgcn_mfma_f32_16x16x32_bf16(a2[ks], w, a, 0, 0, 0);
    }
    #pragma unroll
    for (int r = 0; r < 4; ++r)
      fw[(g*4 + r)*264 + 128 + t*16 + c16] = bfr(a[r] + p_c2[t]);
  }

  __syncthreads();   // make fuse writes visible (also orders ds_write -> ds_read)

  // GEMM3: concat(tf,geo) @ Wf
  bf16x8 a3[8];
  #pragma unroll
  for (int ks = 0; ks < 8; ++ks)
    a3[ks] = *(const bf16x8*)(fw + c16*264 + ks*32 + g*8);
  #pragma unroll
  for (int t = 0; t < 8; ++t) acc[t] = (f32x4){0.f,0.f,0.f,0.f};
  #pragma unroll
  for (int t = 0; t < 8; ++t){
    #pragma unroll
    for (int ks = 0; ks < 8; ++ks){
      bf16x8 w = *(const bf16x8*)(WfT + (t*16 + c16)*256 + ks*32 + g*8);
      acc[t] = __builtin_amdgcn_mfma_f32_16x16x32_bf16(a3[ks], w, acc[t], 0, 0, 0);
    }
  }

  // +bf, LayerNorm, SiLU, alpha/beta
  #pragma unroll
  for (int r = 0; r < 4; ++r){ sm[r] = 0.f; sq[r] = 0.f; }
  #pragma unroll
  for (int t = 0; t < 8; ++t){
    #pragma unroll
    for (int r = 0; r < 4; ++r){
      float v = acc[t][r] + p_bf[t];
      acc[t][r] = v;
      sm[r] += v; sq[r] += v*v;
    }
  }
  #pragma unroll
  for (int mask = 1; mask < 16; mask <<= 1){
    #pragma unroll
    for (int r = 0; r < 4; ++r){ sm[r] += __shfl_xor(sm[r], mask); sq[r] += __shfl_xor(sq[r], mask); }
  }
  #pragma unroll
  for (int r = 0; r < 4; ++r){
    mean[r] = sm[r] * (1.0f/128.0f);
    float var = sq[r]*(1.0f/128.0f) - mean[r]*mean[r];
    rstd[r] = rsqrtf(var + 1e-5f);
  }
  #pragma unroll
  for (int t = 0; t < 8; ++t){
    #pragma unroll
    for (int r = 0; r < 4; ++r){
      float y = (acc[t][r] - mean[r]) * rstd[r] * p_gf[t] + p_ef[t];
      y = y / (1.0f + __expf(-y));
      acc[t][r] = p_al[t]*y + p_bt[t];   // fused (f32)
    }
  }

  // softmax over K=16 rows of rowsum, weighted aggregation
  float sr[4] = {0,0,0,0};
  #pragma unroll
  for (int t = 0; t < 8; ++t){
    #pragma unroll
    for (int r = 0; r < 4; ++r) sr[r] += acc[t][r];
  }
  #pragma unroll
  for (int mask = 1; mask < 16; mask <<= 1){
    #pragma unroll
    for (int r = 0; r < 4; ++r) sr[r] += __shfl_xor(sr[r], mask);
  }
  float mx = fmaxf(fmaxf(sr[0], sr[1]), fmaxf(sr[2], sr[3]));
  mx = fmaxf(mx, __shfl_xor(mx, 16));
  mx = fmaxf(mx, __shfl_xor(mx, 32));
  float e[4]; float se = 0.f;
  #pragma unroll
  for (int r = 0; r < 4; ++r){ e[r] = __expf(sr[r] - mx); se += e[r]; }
  se += __shfl_xor(se, 16);
  se += __shfl_xor(se, 32);
  float inv = 1.0f / se;
  #pragma unroll
  for (int r = 0; r < 4; ++r) e[r] *= inv;

  #pragma unroll
  for (int t = 0; t < 8; ++t){
    float o = e[0]*acc[t][0] + e[1]*acc[t][1] + e[2]*acc[t][2] + e[3]*acc[t][3];
    o += __shfl_xor(o, 16);
    o += __shfl_xor(o, 32);
    if (g == 0) out[point*128 + t*16 + c16] = o;   // f32 output
  }
}

// ---------------- launch ----------------
extern "C" void kernel_launch(void* const* d_in, const int* in_sizes, int n_in,
                              void* d_out, int out_size, void* d_ws, size_t ws_size,
                              hipStream_t stream)
{
  (void)in_sizes; (void)n_in; (void)out_size; (void)ws_size;
  const float* xyz   = (const float*)d_in[0];
  const float* feats = (const float*)d_in[1];
  const float* W1    = (const float*)d_in[2];
  const float* b1    = (const float*)d_in[3];
  const float* ln1g  = (const float*)d_in[4];
  const float* ln1b  = (const float*)d_in[5];
  const float* cw1   = (const float*)d_in[6];
  const float* cb1   = (const float*)d_in[7];
  const float* bng   = (const float*)d_in[8];
  const float* bnb   = (const float*)d_in[9];
  const float* cw2   = (const float*)d_in[10];
  const float* cb2   = (const float*)d_in[11];
  const float* Wf    = (const float*)d_in[12];
  const float* bfb   = (const float*)d_in[13];
  const float* lnfg  = (const float*)d_in[14];
  const float* lnfb  = (const float*)d_in[15];
  const float* alpha = (const float*)d_in[16];
  const float* beta  = (const float*)d_in[17];

  char* ws = (char*)d_ws;
  int*   idx   = (int*)  (ws);                 // 32768*16*4 = 2,097,152 B
  float* stats = (float*)(ws + 2097152);       // 16 floats
  float* bnsc  = (float*)(ws + 2097216);       // 64 floats
  float* bnsh  = (float*)(ws + 2097472);       // 64 floats
  short* W1T   = (short*)(ws + 2097728);       // 32 KB
  short* WfT   = (short*)(ws + 2130496);       // 64 KB
  short* cw2b  = (short*)(ws + 2196032);       // 16 KB

  hipLaunchKernelGGL(prep_kernel, dim3(225), dim3(256), 0, stream,
                     W1, Wf, cw2, W1T, WfT, cw2b, stats);
  hipLaunchKernelGGL(knn_kernel, dim3(512), dim3(512), 0, stream,
                     xyz, idx, stats);
  hipLaunchKernelGGL(bn_finalize_kernel, dim3(1), dim3(64), 0, stream,
                     stats, cw1, cb1, bng, bnb, bnsc, bnsh);
  hipLaunchKernelGGL(lga_main_kernel, dim3(8192), dim3(256), 0, stream,
                     xyz, feats, idx, W1T, WfT, cw2b,
                     b1, ln1g, ln1b, cw1, cb1, bnsc, bnsh,
                     cb2, bfb, lnfg, lnfb, alpha, beta,
                     (float*)d_out);
}

// Round 9
// 1274.804 us; speedup vs baseline: 1.0077x; 1.0077x over previous
//
#include <hip/hip_runtime.h>
#include <hip/hip_bf16.h>

#define B_ 8
#define N_ 4096
#define K_ 16
#define D_ 128

typedef short bf16x8 __attribute__((ext_vector_type(8)));
typedef float f32x4 __attribute__((ext_vector_type(4)));

__device__ __forceinline__ short bfr(float x){
  __hip_bfloat16 h = __float2bfloat16(x);
  return *reinterpret_cast<short*>(&h);
}

// ---------------- prep: bf16 transposed weights + zero stats ----------------
__global__ __launch_bounds__(256) void prep_kernel(
    const float* __restrict__ W1, const float* __restrict__ Wf, const float* __restrict__ cw2,
    short* __restrict__ W1T, short* __restrict__ WfT, short* __restrict__ cw2b,
    float* __restrict__ stats)
{
  int t = blockIdx.x*256 + threadIdx.x;
  if (t < 16384) {                       // W1T[d][c] = W1[c][d]
    int d = t >> 7, c = t & 127;
    W1T[t] = bfr(W1[c*128 + d]);
  } else if (t < 49152) {                // WfT[d][c] = Wf[c][d]
    int u = t - 16384;
    int d = u >> 8, c = u & 255;
    WfT[u] = bfr(Wf[c*128 + d]);
  } else if (t < 57344) {                // cw2 already [d][c] row-major
    int u = t - 49152;
    cw2b[u] = bfr(cw2[u]);
  } else if (t < 57360) {
    stats[t - 57344] = 0.0f;
  }
}

// ---------------- knn ----------------
// plain insert (strict <): ascending within-slice scan => earlier == lower
// index, matching top_k tie semantics.
__device__ __forceinline__ void insert16(float (&bd)[16], int (&bi)[16], float d, int cid){
  #pragma unroll
  for (int j = 15; j >= 1; --j){
    bool ltj = d < bd[j];
    bool ltp = d < bd[j-1];
    float nd = ltj ? (ltp ? bd[j-1] : d) : bd[j];
    int   ni = ltj ? (ltp ? bi[j-1] : cid) : bi[j];
    bd[j] = nd; bi[j] = ni;
  }
  bool lt0 = d < bd[0];
  bd[0] = lt0 ? d : bd[0];
  bi[0] = lt0 ? cid : bi[0];
}

// (d, idx)-lexicographic insert for cross-slice merges: exact-f32 ties resolve
// to the LOWER INDEX regardless of merge-tree order (= top_k).
__device__ __forceinline__ void insert16t(float (&bd)[16], int (&bi)[16], float d, int cid){
  bool lt[16];
  #pragma unroll
  for (int j = 0; j < 16; ++j)
    lt[j] = (d < bd[j]) || ((d == bd[j]) && (cid < bi[j]));
  #pragma unroll
  for (int j = 15; j >= 1; --j){
    float nd = lt[j] ? (lt[j-1] ? bd[j-1] : d) : bd[j];
    int   ni = lt[j] ? (lt[j-1] ? bi[j-1] : cid) : bi[j];
    bd[j] = nd; bi[j] = ni;
  }
  if (lt[0]){ bd[0] = d; bi[0] = cid; }
}

// 512 threads = 8 waves; 64 queries/block; 8 contiguous 512-cand slices per
// query, ascending-index scan. 4-deep register prefetch hides ds_read latency
// under the insert VALU work (R8: 54% VALUBusy from serial load->insert chain).
__global__ __launch_bounds__(512) void knn_kernel(
    const float* __restrict__ xyz, int* __restrict__ idx_out, float* __restrict__ stats)
{
  __shared__ float4 cand[N_];            // 64 KB: x,y,z,|p|^2 (XOR-swizzled)
  int b    = blockIdx.x >> 6;            // 64 blocks per batch
  int qblk = (blockIdx.x & 63) << 6;     // 64 queries per block
  const float* xb = xyz + b*N_*3;
  for (int i = threadIdx.x; i < N_; i += 512){
    float x = xb[i*3+0], y = xb[i*3+1], z = xb[i*3+2];
    int e = i ^ ((i >> 9) & 7);          // swizzled slot (bijection within slice)
    cand[e] = make_float4(x, y, z, x*x + y*y + z*z);
  }
  __syncthreads();

  int wv = threadIdx.x >> 6, lane = threadIdx.x & 63;
  int q = lane & 7;                      // query within wave's 8
  int s = lane >> 3;                     // slice 0..7
  int qi = qblk + (wv << 3) + q;         // batch-local query index
  float4 qc = cand[qi ^ ((qi >> 9) & 7)];

  float bd[16]; int bi[16];
  #pragma unroll
  for (int j = 0; j < 16; ++j){ bd[j] = 3.4e38f; bi[j] = 0x7fffffff; }

  // ascending-index scan of contiguous slice [s*512, (s+1)*512), 4-batched
  // with one-batch-ahead register prefetch (processing order unchanged).
  int cbase = s << 9;
  float4 cb0[4], cb1[4];
  #pragma unroll
  for (int j = 0; j < 4; ++j) cb0[j] = cand[cbase + (j ^ s)];
  for (int m = 0; m < 512; m += 4){
    int mn = (m + 4) & 511;              // wraps to 0 on last batch (unused)
    #pragma unroll
    for (int j = 0; j < 4; ++j) cb1[j] = cand[cbase + ((mn + j) ^ s)];
    #pragma unroll
    for (int j = 0; j < 4; ++j){
      float4 c = cb0[j];
      float t = qc.x*c.x + qc.y*c.y + qc.z*c.z;
      float d = (qc.w + c.w) - 2.0f*t;
      if (d < bd[15]) insert16(bd, bi, d, cbase + m + j);
    }
    #pragma unroll
    for (int j = 0; j < 4; ++j) cb0[j] = cb1[j];
  }

  // absorb-tree merge over slice bits; tie-aware insert makes the result
  // independent of tree order.
  #pragma unroll
  for (int xm = 32; xm >= 8; xm >>= 1){
    bool absorb = (lane & xm) == 0;
    #pragma unroll
    for (int j = 0; j < 16; ++j){
      float pdj = __shfl_xor(bd[j], xm);
      int   pij = __shfl_xor(bi[j], xm);
      if (absorb) insert16t(bd, bi, pdj, pij);
    }
  }

  // lanes with s==0 own the final merged lists
  float sv[9];
  #pragma unroll
  for (int i = 0; i < 9; ++i) sv[i] = 0.0f;
  if (s == 0){
    int gq = b*N_ + qi;
    #pragma unroll
    for (int j = 0; j < 16; ++j){
      idx_out[gq*16 + j] = bi[j];
      int be = bi[j] ^ ((bi[j] >> 9) & 7);
      float4 c = cand[be];
      float rx = c.x - qc.x, ry = c.y - qc.y, rz = c.z - qc.z;
      sv[0] += rx;    sv[1] += ry;    sv[2] += rz;
      sv[3] += rx*rx; sv[4] += ry*ry; sv[5] += rz*rz;
      sv[6] += rx*ry; sv[7] += rx*rz; sv[8] += ry*rz;
    }
  }
  #pragma unroll
  for (int i = 0; i < 9; ++i){
    float v = sv[i];
    #pragma unroll
    for (int mask = 1; mask < 64; mask <<= 1) v += __shfl_xor(v, mask);
    if (lane == 0) atomicAdd(&stats[i], v);
  }
}

// ---------------- BN finalize ----------------
__global__ void bn_finalize_kernel(
    const float* __restrict__ stats, const float* __restrict__ cw1, const float* __restrict__ cb1,
    const float* __restrict__ bn_g, const float* __restrict__ bn_b,
    float* __restrict__ bnsc, float* __restrict__ bnsh)
{
  int o = threadIdx.x;
  if (o >= 64) return;
  const float inv = 1.0f / (float)(B_*N_*K_);
  float m1x = stats[0]*inv, m1y = stats[1]*inv, m1z = stats[2]*inv;
  float mxx = stats[3]*inv, myy = stats[4]*inv, mzz = stats[5]*inv;
  float mxy = stats[6]*inv, mxz = stats[7]*inv, myz = stats[8]*inv;
  float w0 = cw1[o*3], w1 = cw1[o*3+1], w2 = cw1[o*3+2], cb = cb1[o];
  float wm = w0*m1x + w1*m1y + w2*m1z;
  float mu = wm + cb;
  float e2 = w0*w0*mxx + w1*w1*myy + w2*w2*mzz
           + 2.0f*(w0*w1*mxy + w0*w2*mxz + w1*w2*myz)
           + 2.0f*cb*wm + cb*cb;
  float var = e2 - mu*mu;
  float sc = bn_g[o] * rsqrtf(var + 1e-5f);
  bnsc[o] = sc;
  bnsh[o] = bn_b[o] - mu*sc;
}

// ---------------- main fused kernel: 1 wave = 1 point ----------------
__global__ __launch_bounds__(256) void lga_main_kernel(
    const float* __restrict__ xyz, const float* __restrict__ feats, const int* __restrict__ idx_ws,
    const short* __restrict__ W1T, const short* __restrict__ WfT, const short* __restrict__ cw2b,
    const float* __restrict__ b1, const float* __restrict__ ln1g, const float* __restrict__ ln1b,
    const float* __restrict__ cw1, const float* __restrict__ cb1,
    const float* __restrict__ bnsc, const float* __restrict__ bnsh,
    const float* __restrict__ cb2, const float* __restrict__ bfb,
    const float* __restrict__ lnfg, const float* __restrict__ lnfb,
    const float* __restrict__ alpha, const float* __restrict__ beta,
    float* __restrict__ out)
{
  __shared__ short fuse[4][16][264];     // per-wave [16 rows][256+8 cols] bf16 concat buffer
  __shared__ float s_cw1[192], s_cb1[64], s_sc[64], s_sh[64];

  int tid = threadIdx.x;
  for (int i = tid; i < 192; i += 256) s_cw1[i] = cw1[i];
  if (tid < 64){ s_cb1[tid] = cb1[tid]; s_sc[tid] = bnsc[tid]; s_sh[tid] = bnsh[tid]; }
  __syncthreads();

  int wv = tid >> 6, lane = tid & 63, g = lane >> 4, c16 = lane & 15;
  int point = blockIdx.x*4 + wv;
  int bb = point >> 12, n = point & 4095;

  // per-lane column params (col = t*16 + c16)
  float p_b1[8], p_g1[8], p_e1[8], p_c2[8], p_bf[8], p_gf[8], p_ef[8], p_al[8], p_bt[8];
  #pragma unroll
  for (int t = 0; t < 8; ++t){
    int col = t*16 + c16;
    p_b1[t] = b1[col];  p_g1[t] = ln1g[col]; p_e1[t] = ln1b[col]; p_c2[t] = cb2[col];
    p_bf[t] = bfb[col]; p_gf[t] = lnfg[col]; p_ef[t] = lnfb[col];
    p_al[t] = alpha[col]; p_bt[t] = beta[col];
  }

  // A1 fragments: gathered neighbor features (row = c16, k-chunk = g*8 within each 32)
  int nb = idx_ws[point*16 + c16];
  const float* frow = feats + (bb*N_ + nb)*128;
  bf16x8 a1[4];
  #pragma unroll
  for (int ks = 0; ks < 4; ++ks){
    f32x4 lo = *(const f32x4*)(frow + ks*32 + g*8);
    f32x4 hi = *(const f32x4*)(frow + ks*32 + g*8 + 4);
    bf16x8 v;
    v[0]=bfr(lo[0]); v[1]=bfr(lo[1]); v[2]=bfr(lo[2]); v[3]=bfr(lo[3]);
    v[4]=bfr(hi[0]); v[5]=bfr(hi[1]); v[6]=bfr(hi[2]); v[7]=bfr(hi[3]);
    a1[ks] = v;
  }

  // GEMM1: nb_feat @ W1
  f32x4 acc[8];
  #pragma unroll
  for (int t = 0; t < 8; ++t) acc[t] = (f32x4){0.f,0.f,0.f,0.f};
  #pragma unroll
  for (int t = 0; t < 8; ++t){
    #pragma unroll
    for (int ks = 0; ks < 4; ++ks){
      bf16x8 w = *(const bf16x8*)(W1T + (t*16 + c16)*128 + ks*32 + g*8);
      acc[t] = __builtin_amdgcn_mfma_f32_16x16x32_bf16(a1[ks], w, acc[t], 0, 0, 0);
    }
  }

  // +b1, LayerNorm over 128 cols per row, SiLU -> fuse[:, 0:128]
  float sm[4] = {0,0,0,0}, sq[4] = {0,0,0,0};
  #pragma unroll
  for (int t = 0; t < 8; ++t){
    #pragma unroll
    for (int r = 0; r < 4; ++r){
      float v = acc[t][r] + p_b1[t];
      acc[t][r] = v;
      sm[r] += v; sq[r] += v*v;
    }
  }
  #pragma unroll
  for (int mask = 1; mask < 16; mask <<= 1){
    #pragma unroll
    for (int r = 0; r < 4; ++r){ sm[r] += __shfl_xor(sm[r], mask); sq[r] += __shfl_xor(sq[r], mask); }
  }
  float mean[4], rstd[4];
  #pragma unroll
  for (int r = 0; r < 4; ++r){
    mean[r] = sm[r] * (1.0f/128.0f);
    float var = sq[r]*(1.0f/128.0f) - mean[r]*mean[r];
    rstd[r] = rsqrtf(var + 1e-5f);
  }
  short* fw = &fuse[wv][0][0];
  #pragma unroll
  for (int t = 0; t < 8; ++t){
    #pragma unroll
    for (int r = 0; r < 4; ++r){
      float y = (acc[t][r] - mean[r]) * rstd[r] * p_g1[t] + p_e1[t];
      y = y / (1.0f + __expf(-y));       // SiLU
      fw[(g*4 + r)*264 + t*16 + c16] = bfr(y);
    }
  }

  // geo path: rel -> h (VALU, 16 outputs per lane in A2-fragment layout) -> GEMM2b
  float rx, ry, rz;
  {
    const float* cx = xyz + (bb*N_ + n)*3;
    const float* nx = xyz + (bb*N_ + nb)*3;
    rx = nx[0]-cx[0]; ry = nx[1]-cx[1]; rz = nx[2]-cx[2];
  }
  bf16x8 a2[2];
  #pragma unroll
  for (int ks = 0; ks < 2; ++ks){
    bf16x8 v;
    #pragma unroll
    for (int j = 0; j < 8; ++j){
      int o = ks*32 + g*8 + j;
      float h = s_cw1[o*3]*rx + s_cw1[o*3+1]*ry + s_cw1[o*3+2]*rz + s_cb1[o];
      h = h * s_sc[o] + s_sh[o];         // BatchNorm (precomputed global-stat affine)
      h = h / (1.0f + __expf(-h));       // SiLU
      v[j] = bfr(h);
    }
    a2[ks] = v;
  }
  #pragma unroll
  for (int t = 0; t < 8; ++t){
    f32x4 a = (f32x4){0.f,0.f,0.f,0.f};
    #pragma unroll
    for (int ks = 0; ks < 2; ++ks){
      bf16x8 w = *(const bf16x8*)(cw2b + (t*16 + c16)*64 + ks*32 + g*8);
      a = __builtin_amdgcn_mfma_f32_16x16x32_bf16(a2[ks], w, a, 0, 0, 0);
    }
    #pragma unroll
    for (int r = 0; r < 4; ++r)
      fw[(g*4 + r)*264 + 128 + t*16 + c16] = bfr(a[r] + p_c2[t]);
  }

  __syncthreads();   // make fuse writes visible (also orders ds_write -> ds_read)

  // GEMM3: concat(tf,geo) @ Wf
  bf16x8 a3[8];
  #pragma unroll
  for (int ks = 0; ks < 8; ++ks)
    a3[ks] = *(const bf16x8*)(fw + c16*264 + ks*32 + g*8);
  #pragma unroll
  for (int t = 0; t < 8; ++t) acc[t] = (f32x4){0.f,0.f,0.f,0.f};
  #pragma unroll
  for (int t = 0; t < 8; ++t){
    #pragma unroll
    for (int ks = 0; ks < 8; ++ks){
      bf16x8 w = *(const bf16x8*)(WfT + (t*16 + c16)*256 + ks*32 + g*8);
      acc[t] = __builtin_amdgcn_mfma_f32_16x16x32_bf16(a3[ks], w, acc[t], 0, 0, 0);
    }
  }

  // +bf, LayerNorm, SiLU, alpha/beta
  #pragma unroll
  for (int r = 0; r < 4; ++r){ sm[r] = 0.f; sq[r] = 0.f; }
  #pragma unroll
  for (int t = 0; t < 8; ++t){
    #pragma unroll
    for (int r = 0; r < 4; ++r){
      float v = acc[t][r] + p_bf[t];
      acc[t][r] = v;
      sm[r] += v; sq[r] += v*v;
    }
  }
  #pragma unroll
  for (int mask = 1; mask < 16; mask <<= 1){
    #pragma unroll
    for (int r = 0; r < 4; ++r){ sm[r] += __shfl_xor(sm[r], mask); sq[r] += __shfl_xor(sq[r], mask); }
  }
  #pragma unroll
  for (int r = 0; r < 4; ++r){
    mean[r] = sm[r] * (1.0f/128.0f);
    float var = sq[r]*(1.0f/128.0f) - mean[r]*mean[r];
    rstd[r] = rsqrtf(var + 1e-5f);
  }
  #pragma unroll
  for (int t = 0; t < 8; ++t){
    #pragma unroll
    for (int r = 0; r < 4; ++r){
      float y = (acc[t][r] - mean[r]) * rstd[r] * p_gf[t] + p_ef[t];
      y = y / (1.0f + __expf(-y));
      acc[t][r] = p_al[t]*y + p_bt[t];   // fused (f32)
    }
  }

  // softmax over K=16 rows of rowsum, weighted aggregation
  float sr[4] = {0,0,0,0};
  #pragma unroll
  for (int t = 0; t < 8; ++t){
    #pragma unroll
    for (int r = 0; r < 4; ++r) sr[r] += acc[t][r];
  }
  #pragma unroll
  for (int mask = 1; mask < 16; mask <<= 1){
    #pragma unroll
    for (int r = 0; r < 4; ++r) sr[r] += __shfl_xor(sr[r], mask);
  }
  float mx = fmaxf(fmaxf(sr[0], sr[1]), fmaxf(sr[2], sr[3]));
  mx = fmaxf(mx, __shfl_xor(mx, 16));
  mx = fmaxf(mx, __shfl_xor(mx, 32));
  float e[4]; float se = 0.f;
  #pragma unroll
  for (int r = 0; r < 4; ++r){ e[r] = __expf(sr[r] - mx); se += e[r]; }
  se += __shfl_xor(se, 16);
  se += __shfl_xor(se, 32);
  float inv = 1.0f / se;
  #pragma unroll
  for (int r = 0; r < 4; ++r) e[r] *= inv;

  #pragma unroll
  for (int t = 0; t < 8; ++t){
    float o = e[0]*acc[t][0] + e[1]*acc[t][1] + e[2]*acc[t][2] + e[3]*acc[t][3];
    o += __shfl_xor(o, 16);
    o += __shfl_xor(o, 32);
    if (g == 0) out[point*128 + t*16 + c16] = o;   // f32 output
  }
}

// ---------------- launch ----------------
extern "C" void kernel_launch(void* const* d_in, const int* in_sizes, int n_in,
                              void* d_out, int out_size, void* d_ws, size_t ws_size,
                              hipStream_t stream)
{
  (void)in_sizes; (void)n_in; (void)out_size; (void)ws_size;
  const float* xyz   = (const float*)d_in[0];
  const float* feats = (const float*)d_in[1];
  const float* W1    = (const float*)d_in[2];
  const float* b1    = (const float*)d_in[3];
  const float* ln1g  = (const float*)d_in[4];
  const float* ln1b  = (const float*)d_in[5];
  const float* cw1   = (const float*)d_in[6];
  const float* cb1   = (const float*)d_in[7];
  const float* bng   = (const float*)d_in[8];
  const float* bnb   = (const float*)d_in[9];
  const float* cw2   = (const float*)d_in[10];
  const float* cb2   = (const float*)d_in[11];
  const float* Wf    = (const float*)d_in[12];
  const float* bfb   = (const float*)d_in[13];
  const float* lnfg  = (const float*)d_in[14];
  const float* lnfb  = (const float*)d_in[15];
  const float* alpha = (const float*)d_in[16];
  const float* beta  = (const float*)d_in[17];

  char* ws = (char*)d_ws;
  int*   idx   = (int*)  (ws);                 // 32768*16*4 = 2,097,152 B
  float* stats = (float*)(ws + 2097152);       // 16 floats
  float* bnsc  = (float*)(ws + 2097216);       // 64 floats
  float* bnsh  = (float*)(ws + 2097472);       // 64 floats
  short* W1T   = (short*)(ws + 2097728);       // 32 KB
  short* WfT   = (short*)(ws + 2130496);       // 64 KB
  short* cw2b  = (short*)(ws + 2196032);       // 16 KB

  hipLaunchKernelGGL(prep_kernel, dim3(225), dim3(256), 0, stream,
                     W1, Wf, cw2, W1T, WfT, cw2b, stats);
  hipLaunchKernelGGL(knn_kernel, dim3(512), dim3(512), 0, stream,
                     xyz, idx, stats);
  hipLaunchKernelGGL(bn_finalize_kernel, dim3(1), dim3(64), 0, stream,
                     stats, cw1, cb1, bng, bnb, bnsc, bnsh);
  hipLaunchKernelGGL(lga_main_kernel, dim3(8192), dim3(256), 0, stream,
                     xyz, feats, idx, W1T, WfT, cw2b,
                     b1, ln1g, ln1b, cw1, cb1, bnsc, bnsh,
                     cb2, bfb, lnfg, lnfb, alpha, beta,
                     (float*)d_out);
}